// Round 9
// baseline (162.292 us; speedup 1.0000x reference)
//
#include <hip/hip_runtime.h>
#include <math.h>

#define BB 16
#define SS 8192
#define DD 512
#define HH 512
#define NEG_INF (-1e18f)
#define BPB 64   // score-blocks per batch: 16*64 = 1024 blocks

__device__ __forceinline__ float dot8(float4 a0, float4 a1, float4 b0, float4 b1) {
  return a0.x*b0.x + a0.y*b0.y + a0.z*b0.z + a0.w*b0.w
       + a1.x*b1.x + a1.y*b1.y + a1.z*b1.z + a1.w*b1.w;
}

// DPP wave64 sum: result valid in lane 63 only. VALU-only (no DS pipe).
template <int CTRL>
__device__ __forceinline__ float dpp_add0(float x) {
  return x + __int_as_float(__builtin_amdgcn_update_dpp(
      0, __float_as_int(x), CTRL, 0xf, 0xf, true));
}
__device__ __forceinline__ float wave_red_sum(float x) {
  x = dpp_add0<0x111>(x);  // row_shr:1
  x = dpp_add0<0x112>(x);  // row_shr:2
  x = dpp_add0<0x114>(x);  // row_shr:4
  x = dpp_add0<0x118>(x);  // row_shr:8
  x = dpp_add0<0x142>(x);  // row_bcast:15
  x = dpp_add0<0x143>(x);  // row_bcast:31
  return x;                // lane 63 = full sum
}
__device__ __forceinline__ float lane63(float x) {
  return __int_as_float(__builtin_amdgcn_readlane(__float_as_int(x), 63));
}

// K0: 129 blocks x 256 threads (unchanged).
__global__ __launch_bounds__(256) void k_prep(
    const float* __restrict__ Wq, const float* __restrict__ Wk,
    const float* __restrict__ wout, const float* __restrict__ bq,
    const float* __restrict__ bk, float* __restrict__ v,
    float* __restrict__ w2, float* __restrict__ c0)
{
  int blk = blockIdx.x;
  int t = threadIdx.x;
  if (blk == 128) {
    if (t < 64) {
      float part = 0.f;
      #pragma unroll
      for (int i = 0; i < 8; ++i) {
        int h = t + 64 * i;
        part += wout[h] * (bq[h] + bk[h]);
      }
      part = wave_red_sum(part);
      if (t == 63) c0[0] = part;
    }
    return;
  }
  int j = blk & 63;
  const float* W = (blk < 64) ? Wk : Wq;
  float* outp = (blk < 64) ? v : w2;
  int dsl = j * 8;
  int h0 = t, h1 = t + 256;
  const float4* r0 = (const float4*)(W + (size_t)h0 * DD + dsl);
  const float4* r1 = (const float4*)(W + (size_t)h1 * DD + dsl);
  float4 a0 = r0[0], a1 = r0[1], b0 = r1[0], b1 = r1[1];
  float wA = wout[h0], wB = wout[h1];
  float acc[8];
  acc[0] = wA*a0.x + wB*b0.x; acc[1] = wA*a0.y + wB*b0.y;
  acc[2] = wA*a0.z + wB*b0.z; acc[3] = wA*a0.w + wB*b0.w;
  acc[4] = wA*a1.x + wB*b1.x; acc[5] = wA*a1.y + wB*b1.y;
  acc[6] = wA*a1.z + wB*b1.z; acc[7] = wA*a1.w + wB*b1.w;
  __shared__ float red[256][9];
  #pragma unroll
  for (int k = 0; k < 8; ++k) red[t][k] = acc[k];
  __syncthreads();
  for (int st = 128; st; st >>= 1) {
    if (t < st) {
      #pragma unroll
      for (int k = 0; k < 8; ++k) red[t][k] += red[t + st][k];
    }
    __syncthreads();
  }
  if (t < 8) outp[dsl + t] = red[0][t];
}

// K1: main streaming pass. grid = B*BPB blocks x 256 threads (4 waves).
// 4 rows/wave/iter; FULL UNROLL (nit=8) + bounds(256,3) so the scheduler can
// hoist load groups ~2 iterations deep. No online max: p = exp(key.v), the
// per-b constant qc cancels in softmax (|key.v| <~ 35 so exp fits f32).
__global__ __launch_bounds__(256, 3) void k_score(
    const float* __restrict__ key, const int* __restrict__ mask,
    const float* __restrict__ query, const float* __restrict__ ws_v,
    const float* __restrict__ ws_w2, const float* __restrict__ ws_c0,
    float* __restrict__ scores, float* __restrict__ partials)
{
  int blk = blockIdx.x;
  int b = blk / BPB;
  int pb = blk % BPB;
  const int rows = SS / BPB;       // 128
  int s0 = pb * rows;
  int wave = threadIdx.x >> 6;
  int lane = threadIdx.x & 63;

  const float4* vv = (const float4*)ws_v;
  float4 v0 = vv[lane], v1 = vv[64 + lane];

  // qc = query[b].w2 + c0 (only needed for the scores output)
  float qc;
  {
    const float4* q4 = (const float4*)(query + (size_t)b * DD);
    const float4* w24 = (const float4*)ws_w2;
    float qp = wave_red_sum(dot8(q4[lane], q4[64 + lane], w24[lane], w24[64 + lane]));
    qc = lane63(qp) + ws_c0[0];
  }

  const float4* keyb = (const float4*)(key + (size_t)b * SS * DD);
  const int* maskb = mask + b * SS;

  float l = 0.f;
  float4 u0 = {0.f,0.f,0.f,0.f}, u1 = {0.f,0.f,0.f,0.f};

  const int nit = rows / 16;  // 8 iterations, 16 rows/block/iter
  int s = s0 + wave * 4;

  float4 r0a, r0b, r1a, r1b, r2a, r2b, r3a, r3b;
  {
    const float4* p0 = keyb + (size_t)s * (DD / 4);
    r0a = p0[lane];       r0b = p0[64 + lane];
    r1a = p0[128 + lane]; r1b = p0[192 + lane];
    r2a = p0[256 + lane]; r2b = p0[320 + lane];
    r3a = p0[384 + lane]; r3b = p0[448 + lane];
  }
  int4 mk = *(const int4*)(maskb + s);

  #pragma unroll
  for (int i = 0; i < nit; ++i) {
    float4 n0a=r0a, n0b=r0b, n1a=r1a, n1b=r1b, n2a=r2a, n2b=r2b, n3a=r3a, n3b=r3b;
    int4 nmk = {0,0,0,0};
    if (i + 1 < nit) {
      const float4* p0 = keyb + (size_t)(s + 16) * (DD / 4);
      n0a = p0[lane];       n0b = p0[64 + lane];
      n1a = p0[128 + lane]; n1b = p0[192 + lane];
      n2a = p0[256 + lane]; n2b = p0[320 + lane];
      n3a = p0[384 + lane]; n3b = p0[448 + lane];
      nmk = *(const int4*)(maskb + s + 16);
    }
    // 4 independent DPP reduce chains (VALU only)
    float p0v = wave_red_sum(dot8(r0a, r0b, v0, v1));
    float p1v = wave_red_sum(dot8(r1a, r1b, v0, v1));
    float p2v = wave_red_sum(dot8(r2a, r2b, v0, v1));
    float p3v = wave_red_sum(dot8(r3a, r3b, v0, v1));
    float d0 = lane63(p0v), d1 = lane63(p1v);
    float d2 = lane63(p2v), d3 = lane63(p3v);
    if (lane == 0) {
      float4 st;
      st.x = mk.x ? NEG_INF : (d0 + qc);
      st.y = mk.y ? NEG_INF : (d1 + qc);
      st.z = mk.z ? NEG_INF : (d2 + qc);
      st.w = mk.w ? NEG_INF : (d3 + qc);
      *(float4*)(scores + (size_t)b * SS + s) = st;
    }
    float e0 = mk.x ? 0.f : __expf(d0);
    float e1 = mk.y ? 0.f : __expf(d1);
    float e2 = mk.z ? 0.f : __expf(d2);
    float e3 = mk.w ? 0.f : __expf(d3);
    l += (e0 + e1) + (e2 + e3);
    u0.x += e0*r0a.x + e1*r1a.x + e2*r2a.x + e3*r3a.x;
    u0.y += e0*r0a.y + e1*r1a.y + e2*r2a.y + e3*r3a.y;
    u0.z += e0*r0a.z + e1*r1a.z + e2*r2a.z + e3*r3a.z;
    u0.w += e0*r0a.w + e1*r1a.w + e2*r2a.w + e3*r3a.w;
    u1.x += e0*r0b.x + e1*r1b.x + e2*r2b.x + e3*r3b.x;
    u1.y += e0*r0b.y + e1*r1b.y + e2*r2b.y + e3*r3b.y;
    u1.z += e0*r0b.z + e1*r1b.z + e2*r2b.z + e3*r3b.z;
    u1.w += e0*r0b.w + e1*r1b.w + e2*r2b.w + e3*r3b.w;
    r0a=n0a; r0b=n0b; r1a=n1a; r1b=n1b; r2a=n2a; r2b=n2b; r3a=n3a; r3b=n3b;
    mk = nmk; s += 16;
  }

  // block combine across 4 waves: plain sums (no max weighting needed)
  __shared__ float ls_l[4];
  __shared__ __align__(16) float ls_u[4][DD];
  ls_u[wave][4 * lane + 0] = u0.x; ls_u[wave][4 * lane + 1] = u0.y;
  ls_u[wave][4 * lane + 2] = u0.z; ls_u[wave][4 * lane + 3] = u0.w;
  ls_u[wave][256 + 4 * lane + 0] = u1.x; ls_u[wave][256 + 4 * lane + 1] = u1.y;
  ls_u[wave][256 + 4 * lane + 2] = u1.z; ls_u[wave][256 + 4 * lane + 3] = u1.w;
  if (lane == 0) ls_l[wave] = l;
  __syncthreads();

  int d = threadIdx.x;  // 0..255
  float ua = ls_u[0][d] + ls_u[1][d] + ls_u[2][d] + ls_u[3][d];
  float ub = ls_u[0][d + 256] + ls_u[1][d + 256] + ls_u[2][d + 256] + ls_u[3][d + 256];
  float* part = partials + (size_t)(b * BPB + pb) * (DD + 2);
  part[2 + d] = ua;
  part[2 + 256 + d] = ub;
  if (threadIdx.x == 0) {
    part[0] = ls_l[0] + ls_l[1] + ls_l[2] + ls_l[3];
  }
}

// K2: fused combine + attn. 256 blocks (b, hc) x 256 threads.
__global__ __launch_bounds__(256) void k_out(
    const float* __restrict__ Wk, const float* __restrict__ bk,
    const float* __restrict__ partials, float* __restrict__ attn)
{
  int b = blockIdx.x >> 4;
  int hc = blockIdx.x & 15;
  int tid = threadIdx.x;
  int wave = tid >> 6, lane = tid & 63;
  __shared__ __align__(16) float ubar[DD];
  __shared__ float dsh;
  const float* pbase = partials + (size_t)b * BPB * (DD + 2);

  if (tid < 64) {
    float lp = pbase[tid * (DD + 2)];
    float dn = wave_red_sum(lp);
    if (tid == 63) dsh = dn;
  }
  __syncthreads();

  float inv = 1.f / dsh;
  float ua = 0.f, ub_ = 0.f;
  #pragma unroll 8
  for (int p = 0; p < BPB; ++p) {
    ua  += pbase[p * (DD + 2) + 2 + tid];
    ub_ += pbase[p * (DD + 2) + 2 + 256 + tid];
  }
  ubar[tid] = ua * inv;
  ubar[tid + 256] = ub_ * inv;
  __syncthreads();

  const float4* ub4 = (const float4*)ubar;
  float4 x0 = ub4[lane], x1 = ub4[64 + lane];
  #pragma unroll
  for (int j = 0; j < 8; ++j) {
    int h = hc * 32 + wave * 8 + j;
    const float4* wr = (const float4*)(Wk + (size_t)h * DD);
    float p = wave_red_sum(dot8(wr[lane], wr[64 + lane], x0, x1));
    if (lane == 63) attn[b * HH + h] = p + bk[h];
  }
}

extern "C" void kernel_launch(void* const* d_in, const int* in_sizes, int n_in,
                              void* d_out, int out_size, void* d_ws, size_t ws_size,
                              hipStream_t stream) {
  const float* query = (const float*)d_in[0];
  const float* key   = (const float*)d_in[1];
  const int*   mask  = (const int*)d_in[2];
  const float* Wq    = (const float*)d_in[3];
  const float* bq    = (const float*)d_in[4];
  const float* Wk    = (const float*)d_in[5];
  const float* bk    = (const float*)d_in[6];
  const float* wout  = (const float*)d_in[7];

  float* out    = (float*)d_out;
  float* attn   = out;                 // (B, H)
  float* scores = out + BB * HH;       // (B, S)
  float* ws     = (float*)d_ws;

  // ws layout (floats)
  float* ws_v  = ws;            // 512
  float* ws_w2 = ws + 512;      // 512
  float* ws_c0 = ws + 1024;     // 1 (pad to 1040)
  float* partials = ws + 1040;  // B*BPB*(D+2) ~ 2.06 MB

  k_prep<<<dim3(129), dim3(256), 0, stream>>>(Wq, Wk, wout, bq, bk,
                                              ws_v, ws_w2, ws_c0);
  k_score<<<dim3(BB * BPB), dim3(256), 0, stream>>>(key, mask, query, ws_v,
                                                    ws_w2, ws_c0, scores, partials);
  k_out<<<dim3(BB * 16), dim3(256), 0, stream>>>(Wk, bk, partials, attn);
}

// Round 10
// 59.687 us; speedup vs baseline: 2.7190x; 2.7190x over previous
//
#include <hip/hip_runtime.h>
#include <math.h>

#define BB 16
#define SS 8192
#define DD 512
#define HH 512
#define NEG_INF (-1e18f)
#define BPB 64   // score-blocks per batch: 16*64 = 1024 blocks = 4 per CU

__device__ __forceinline__ float dot8(float4 a0, float4 a1, float4 b0, float4 b1) {
  return a0.x*b0.x + a0.y*b0.y + a0.z*b0.z + a0.w*b0.w
       + a1.x*b1.x + a1.y*b1.y + a1.z*b1.z + a1.w*b1.w;
}

// DPP wave64 sum: result valid in lane 63 only. VALU-only (no DS pipe).
template <int CTRL>
__device__ __forceinline__ float dpp_add0(float x) {
  return x + __int_as_float(__builtin_amdgcn_update_dpp(
      0, __float_as_int(x), CTRL, 0xf, 0xf, true));
}
__device__ __forceinline__ float wave_red_sum(float x) {
  x = dpp_add0<0x111>(x);  // row_shr:1
  x = dpp_add0<0x112>(x);  // row_shr:2
  x = dpp_add0<0x114>(x);  // row_shr:4
  x = dpp_add0<0x118>(x);  // row_shr:8
  x = dpp_add0<0x142>(x);  // row_bcast:15
  x = dpp_add0<0x143>(x);  // row_bcast:31
  return x;                // lane 63 = full sum
}
__device__ __forceinline__ float lane63(float x) {
  return __int_as_float(__builtin_amdgcn_readlane(__float_as_int(x), 63));
}

// K0: 129 blocks x 256 threads (unchanged from R5).
__global__ __launch_bounds__(256) void k_prep(
    const float* __restrict__ Wq, const float* __restrict__ Wk,
    const float* __restrict__ wout, const float* __restrict__ bq,
    const float* __restrict__ bk, float* __restrict__ v,
    float* __restrict__ w2, float* __restrict__ c0)
{
  int blk = blockIdx.x;
  int t = threadIdx.x;
  if (blk == 128) {
    if (t < 64) {
      float part = 0.f;
      #pragma unroll
      for (int i = 0; i < 8; ++i) {
        int h = t + 64 * i;
        part += wout[h] * (bq[h] + bk[h]);
      }
      part = wave_red_sum(part);
      if (t == 63) c0[0] = part;
    }
    return;
  }
  int j = blk & 63;
  const float* W = (blk < 64) ? Wk : Wq;
  float* outp = (blk < 64) ? v : w2;
  int dsl = j * 8;
  int h0 = t, h1 = t + 256;
  const float4* r0 = (const float4*)(W + (size_t)h0 * DD + dsl);
  const float4* r1 = (const float4*)(W + (size_t)h1 * DD + dsl);
  float4 a0 = r0[0], a1 = r0[1], b0 = r1[0], b1 = r1[1];
  float wA = wout[h0], wB = wout[h1];
  float acc[8];
  acc[0] = wA*a0.x + wB*b0.x; acc[1] = wA*a0.y + wB*b0.y;
  acc[2] = wA*a0.z + wB*b0.z; acc[3] = wA*a0.w + wB*b0.w;
  acc[4] = wA*a1.x + wB*b1.x; acc[5] = wA*a1.y + wB*b1.y;
  acc[6] = wA*a1.z + wB*b1.z; acc[7] = wA*a1.w + wB*b1.w;
  __shared__ float red[256][9];
  #pragma unroll
  for (int k = 0; k < 8; ++k) red[t][k] = acc[k];
  __syncthreads();
  for (int st = 128; st; st >>= 1) {
    if (t < st) {
      #pragma unroll
      for (int k = 0; k < 8; ++k) red[t][k] += red[t + st][k];
    }
    __syncthreads();
  }
  if (t < 8) outp[dsl + t] = red[0][t];
}

// K1: main streaming pass. grid = B*BPB blocks x 256 threads (4 waves).
// 4 rows/wave/iter, depth-1 prefetch, DPP reductions, ROLLED loop,
// bounds(256,4) (the proven R5 schedule). No online max: p = exp(key.v),
// the per-b constant qc cancels in softmax (|key.v| <~ 35 fits f32).
__global__ __launch_bounds__(256, 4) void k_score(
    const float* __restrict__ key, const int* __restrict__ mask,
    const float* __restrict__ query, const float* __restrict__ ws_v,
    const float* __restrict__ ws_w2, const float* __restrict__ ws_c0,
    float* __restrict__ scores, float* __restrict__ partials)
{
  int blk = blockIdx.x;
  int b = blk / BPB;
  int pb = blk % BPB;
  const int rows = SS / BPB;       // 128
  int s0 = pb * rows;
  int wave = threadIdx.x >> 6;
  int lane = threadIdx.x & 63;

  const float4* vv = (const float4*)ws_v;
  float4 v0 = vv[lane], v1 = vv[64 + lane];

  // qc = query[b].w2 + c0 (only needed for the scores output)
  float qc;
  {
    const float4* q4 = (const float4*)(query + (size_t)b * DD);
    const float4* w24 = (const float4*)ws_w2;
    float qp = wave_red_sum(dot8(q4[lane], q4[64 + lane], w24[lane], w24[64 + lane]));
    qc = lane63(qp) + ws_c0[0];
  }

  const float4* keyb = (const float4*)(key + (size_t)b * SS * DD);
  const int* maskb = mask + b * SS;

  float l = 0.f;
  float4 u0 = {0.f,0.f,0.f,0.f}, u1 = {0.f,0.f,0.f,0.f};

  const int nit = rows / 16;  // 8 iterations, 16 rows/block/iter
  int s = s0 + wave * 4;

  float4 r0a, r0b, r1a, r1b, r2a, r2b, r3a, r3b;
  {
    const float4* p0 = keyb + (size_t)s * (DD / 4);
    r0a = p0[lane];       r0b = p0[64 + lane];
    r1a = p0[128 + lane]; r1b = p0[192 + lane];
    r2a = p0[256 + lane]; r2b = p0[320 + lane];
    r3a = p0[384 + lane]; r3b = p0[448 + lane];
  }
  int4 mk = *(const int4*)(maskb + s);

  for (int i = 0; i < nit; ++i) {
    float4 n0a=r0a, n0b=r0b, n1a=r1a, n1b=r1b, n2a=r2a, n2b=r2b, n3a=r3a, n3b=r3b;
    int4 nmk = {0,0,0,0};
    if (i + 1 < nit) {
      const float4* p0 = keyb + (size_t)(s + 16) * (DD / 4);
      n0a = p0[lane];       n0b = p0[64 + lane];
      n1a = p0[128 + lane]; n1b = p0[192 + lane];
      n2a = p0[256 + lane]; n2b = p0[320 + lane];
      n3a = p0[384 + lane]; n3b = p0[448 + lane];
      nmk = *(const int4*)(maskb + s + 16);
    }
    // 4 independent DPP reduce chains (VALU only)
    float p0v = wave_red_sum(dot8(r0a, r0b, v0, v1));
    float p1v = wave_red_sum(dot8(r1a, r1b, v0, v1));
    float p2v = wave_red_sum(dot8(r2a, r2b, v0, v1));
    float p3v = wave_red_sum(dot8(r3a, r3b, v0, v1));
    float d0 = lane63(p0v), d1 = lane63(p1v);
    float d2 = lane63(p2v), d3 = lane63(p3v);
    if (lane == 0) {
      float4 st;
      st.x = mk.x ? NEG_INF : (d0 + qc);
      st.y = mk.y ? NEG_INF : (d1 + qc);
      st.z = mk.z ? NEG_INF : (d2 + qc);
      st.w = mk.w ? NEG_INF : (d3 + qc);
      *(float4*)(scores + (size_t)b * SS + s) = st;
    }
    float e0 = mk.x ? 0.f : __expf(d0);
    float e1 = mk.y ? 0.f : __expf(d1);
    float e2 = mk.z ? 0.f : __expf(d2);
    float e3 = mk.w ? 0.f : __expf(d3);
    l += (e0 + e1) + (e2 + e3);
    u0.x += e0*r0a.x + e1*r1a.x + e2*r2a.x + e3*r3a.x;
    u0.y += e0*r0a.y + e1*r1a.y + e2*r2a.y + e3*r3a.y;
    u0.z += e0*r0a.z + e1*r1a.z + e2*r2a.z + e3*r3a.z;
    u0.w += e0*r0a.w + e1*r1a.w + e2*r2a.w + e3*r3a.w;
    u1.x += e0*r0b.x + e1*r1b.x + e2*r2b.x + e3*r3b.x;
    u1.y += e0*r0b.y + e1*r1b.y + e2*r2b.y + e3*r3b.y;
    u1.z += e0*r0b.z + e1*r1b.z + e2*r2b.z + e3*r3b.z;
    u1.w += e0*r0b.w + e1*r1b.w + e2*r2b.w + e3*r3b.w;
    r0a=n0a; r0b=n0b; r1a=n1a; r1b=n1b; r2a=n2a; r2b=n2b; r3a=n3a; r3b=n3b;
    mk = nmk; s += 16;
  }

  // block combine across 4 waves: plain sums (no max weighting needed)
  __shared__ float ls_l[4];
  __shared__ __align__(16) float ls_u[4][DD];
  ls_u[wave][4 * lane + 0] = u0.x; ls_u[wave][4 * lane + 1] = u0.y;
  ls_u[wave][4 * lane + 2] = u0.z; ls_u[wave][4 * lane + 3] = u0.w;
  ls_u[wave][256 + 4 * lane + 0] = u1.x; ls_u[wave][256 + 4 * lane + 1] = u1.y;
  ls_u[wave][256 + 4 * lane + 2] = u1.z; ls_u[wave][256 + 4 * lane + 3] = u1.w;
  if (lane == 0) ls_l[wave] = l;
  __syncthreads();

  int d = threadIdx.x;  // 0..255
  float ua = ls_u[0][d] + ls_u[1][d] + ls_u[2][d] + ls_u[3][d];
  float ub = ls_u[0][d + 256] + ls_u[1][d + 256] + ls_u[2][d + 256] + ls_u[3][d + 256];
  float* part = partials + (size_t)(b * BPB + pb) * (DD + 2);
  part[2 + d] = ua;
  part[2 + 256 + d] = ub;
  if (threadIdx.x == 0) {
    part[0] = ls_l[0] + ls_l[1] + ls_l[2] + ls_l[3];
  }
}

// K2: fused combine + attn. 256 blocks (b, hc) x 256 threads.
__global__ __launch_bounds__(256) void k_out(
    const float* __restrict__ Wk, const float* __restrict__ bk,
    const float* __restrict__ partials, float* __restrict__ attn)
{
  int b = blockIdx.x >> 4;
  int hc = blockIdx.x & 15;
  int tid = threadIdx.x;
  int wave = tid >> 6, lane = tid & 63;
  __shared__ __align__(16) float ubar[DD];
  __shared__ float dsh;
  const float* pbase = partials + (size_t)b * BPB * (DD + 2);

  if (tid < 64) {
    float lp = pbase[tid * (DD + 2)];
    float dn = wave_red_sum(lp);
    if (tid == 63) dsh = dn;
  }
  __syncthreads();

  float inv = 1.f / dsh;
  float ua = 0.f, ub_ = 0.f;
  #pragma unroll 8
  for (int p = 0; p < BPB; ++p) {
    ua  += pbase[p * (DD + 2) + 2 + tid];
    ub_ += pbase[p * (DD + 2) + 2 + 256 + tid];
  }
  ubar[tid] = ua * inv;
  ubar[tid + 256] = ub_ * inv;
  __syncthreads();

  const float4* ub4 = (const float4*)ubar;
  float4 x0 = ub4[lane], x1 = ub4[64 + lane];
  #pragma unroll
  for (int j = 0; j < 8; ++j) {
    int h = hc * 32 + wave * 8 + j;
    const float4* wr = (const float4*)(Wk + (size_t)h * DD);
    float p = wave_red_sum(dot8(wr[lane], wr[64 + lane], x0, x1));
    if (lane == 63) attn[b * HH + h] = p + bk[h];
  }
}

extern "C" void kernel_launch(void* const* d_in, const int* in_sizes, int n_in,
                              void* d_out, int out_size, void* d_ws, size_t ws_size,
                              hipStream_t stream) {
  const float* query = (const float*)d_in[0];
  const float* key   = (const float*)d_in[1];
  const int*   mask  = (const int*)d_in[2];
  const float* Wq    = (const float*)d_in[3];
  const float* bq    = (const float*)d_in[4];
  const float* Wk    = (const float*)d_in[5];
  const float* bk    = (const float*)d_in[6];
  const float* wout  = (const float*)d_in[7];

  float* out    = (float*)d_out;
  float* attn   = out;                 // (B, H)
  float* scores = out + BB * HH;       // (B, S)
  float* ws     = (float*)d_ws;

  // ws layout (floats)
  float* ws_v  = ws;            // 512
  float* ws_w2 = ws + 512;      // 512
  float* ws_c0 = ws + 1024;     // 1 (pad to 1040)
  float* partials = ws + 1040;  // B*BPB*(D+2) ~ 2.06 MB

  k_prep<<<dim3(129), dim3(256), 0, stream>>>(Wq, Wk, wout, bq, bk,
                                              ws_v, ws_w2, ws_c0);
  k_score<<<dim3(BB * BPB), dim3(256), 0, stream>>>(key, mask, query, ws_v,
                                                    ws_w2, ws_c0, scores, partials);
  k_out<<<dim3(BB * 16), dim3(256), 0, stream>>>(Wk, bk, partials, attn);
}

// Round 11
// 59.476 us; speedup vs baseline: 2.7287x; 1.0036x over previous
//
#include <hip/hip_runtime.h>
#include <math.h>

#define BB 16
#define SS 8192
#define DD 512
#define HH 512
#define NEG_INF (-1e18f)
#define BPB 64   // score-blocks per batch: 16*64 = 1024 blocks = 4 per CU

__device__ __forceinline__ float dot8(float4 a0, float4 a1, float4 b0, float4 b1) {
  return a0.x*b0.x + a0.y*b0.y + a0.z*b0.z + a0.w*b0.w
       + a1.x*b1.x + a1.y*b1.y + a1.z*b1.z + a1.w*b1.w;
}

// DPP wave64 sum: result valid in lane 63 only. VALU-only (no DS pipe).
template <int CTRL>
__device__ __forceinline__ float dpp_add0(float x) {
  return x + __int_as_float(__builtin_amdgcn_update_dpp(
      0, __float_as_int(x), CTRL, 0xf, 0xf, true));
}
__device__ __forceinline__ float wave_red_sum(float x) {
  x = dpp_add0<0x111>(x);  // row_shr:1
  x = dpp_add0<0x112>(x);  // row_shr:2
  x = dpp_add0<0x114>(x);  // row_shr:4
  x = dpp_add0<0x118>(x);  // row_shr:8
  x = dpp_add0<0x142>(x);  // row_bcast:15
  x = dpp_add0<0x143>(x);  // row_bcast:31
  return x;                // lane 63 = full sum
}
__device__ __forceinline__ float lane63(float x) {
  return __int_as_float(__builtin_amdgcn_readlane(__float_as_int(x), 63));
}

// K0: 129 blocks x 256 threads (unchanged).
__global__ __launch_bounds__(256) void k_prep(
    const float* __restrict__ Wq, const float* __restrict__ Wk,
    const float* __restrict__ wout, const float* __restrict__ bq,
    const float* __restrict__ bk, float* __restrict__ v,
    float* __restrict__ w2, float* __restrict__ c0)
{
  int blk = blockIdx.x;
  int t = threadIdx.x;
  if (blk == 128) {
    if (t < 64) {
      float part = 0.f;
      #pragma unroll
      for (int i = 0; i < 8; ++i) {
        int h = t + 64 * i;
        part += wout[h] * (bq[h] + bk[h]);
      }
      part = wave_red_sum(part);
      if (t == 63) c0[0] = part;
    }
    return;
  }
  int j = blk & 63;
  const float* W = (blk < 64) ? Wk : Wq;
  float* outp = (blk < 64) ? v : w2;
  int dsl = j * 8;
  int h0 = t, h1 = t + 256;
  const float4* r0 = (const float4*)(W + (size_t)h0 * DD + dsl);
  const float4* r1 = (const float4*)(W + (size_t)h1 * DD + dsl);
  float4 a0 = r0[0], a1 = r0[1], b0 = r1[0], b1 = r1[1];
  float wA = wout[h0], wB = wout[h1];
  float acc[8];
  acc[0] = wA*a0.x + wB*b0.x; acc[1] = wA*a0.y + wB*b0.y;
  acc[2] = wA*a0.z + wB*b0.z; acc[3] = wA*a0.w + wB*b0.w;
  acc[4] = wA*a1.x + wB*b1.x; acc[5] = wA*a1.y + wB*b1.y;
  acc[6] = wA*a1.z + wB*b1.z; acc[7] = wA*a1.w + wB*b1.w;
  __shared__ float red[256][9];
  #pragma unroll
  for (int k = 0; k < 8; ++k) red[t][k] = acc[k];
  __syncthreads();
  for (int st = 128; st; st >>= 1) {
    if (t < st) {
      #pragma unroll
      for (int k = 0; k < 8; ++k) red[t][k] += red[t + st][k];
    }
    __syncthreads();
  }
  if (t < 8) outp[dsl + t] = red[0][t];
}

// K1: main streaming pass. grid = B*BPB blocks x 256 threads (4 waves).
// 2 rows/wave/iter with DEPTH-2 prefetch (3 named buffer sets A/B/C, rolled
// loop, no arrays -> no scratch). bounds(256,4), DPP reductions, no online
// max (p = exp(key.v); per-b qc cancels in softmax, |key.v| <~ 35 fits f32).
__global__ __launch_bounds__(256, 4) void k_score(
    const float* __restrict__ key, const int* __restrict__ mask,
    const float* __restrict__ query, const float* __restrict__ ws_v,
    const float* __restrict__ ws_w2, const float* __restrict__ ws_c0,
    float* __restrict__ scores, float* __restrict__ partials)
{
  int blk = blockIdx.x;
  int b = blk / BPB;
  int pb = blk % BPB;
  const int rows = SS / BPB;       // 128
  int s0 = pb * rows;
  int wave = threadIdx.x >> 6;
  int lane = threadIdx.x & 63;

  const float4* vv = (const float4*)ws_v;
  float4 v0 = vv[lane], v1 = vv[64 + lane];

  // qc = query[b].w2 + c0 (only needed for the scores output)
  float qc;
  {
    const float4* q4 = (const float4*)(query + (size_t)b * DD);
    const float4* w24 = (const float4*)ws_w2;
    float qp = wave_red_sum(dot8(q4[lane], q4[64 + lane], w24[lane], w24[64 + lane]));
    qc = lane63(qp) + ws_c0[0];
  }

  const float4* keyb = (const float4*)(key + (size_t)b * SS * DD);
  const int* maskb = mask + b * SS;

  float l = 0.f;
  float4 u0 = {0.f,0.f,0.f,0.f}, u1 = {0.f,0.f,0.f,0.f};

  const int nit = rows / 8;   // 16 iterations, 8 rows/block/iter (4 waves x 2)
  int s = s0 + wave * 2;      // this wave's first row pair

  // Buffer sets: A = iter i (compute), B = iter i+1, C = iter i+2 (in flight)
  float4 a0a, a0b, a1a, a1b;  // A: rows s, s+1
  float4 b0a, b0b, b1a, b1b;  // B: rows s+8, s+9
  int2 mkA, mkB;
  {
    const float4* pA = keyb + (size_t)s * (DD / 4);
    a0a = pA[lane];       a0b = pA[64 + lane];
    a1a = pA[128 + lane]; a1b = pA[192 + lane];
    mkA = *(const int2*)(maskb + s);
    const float4* pB = keyb + (size_t)(s + 8) * (DD / 4);
    b0a = pB[lane];       b0b = pB[64 + lane];
    b1a = pB[128 + lane]; b1b = pB[192 + lane];
    mkB = *(const int2*)(maskb + s + 8);
  }

  for (int i = 0; i < nit; ++i) {
    // issue depth-2 prefetch into C
    float4 c0a = a0a, c0b = a0b, c1a = a1a, c1b = a1b;
    int2 mkC = {0, 0};
    if (i + 2 < nit) {
      const float4* pC = keyb + (size_t)(s + 16) * (DD / 4);
      c0a = pC[lane];       c0b = pC[64 + lane];
      c1a = pC[128 + lane]; c1b = pC[192 + lane];
      mkC = *(const int2*)(maskb + s + 16);
    }
    // compute on A (2 independent DPP reduce chains, VALU only)
    float p0v = wave_red_sum(dot8(a0a, a0b, v0, v1));
    float p1v = wave_red_sum(dot8(a1a, a1b, v0, v1));
    float d0 = lane63(p0v), d1 = lane63(p1v);
    if (lane == 0) {
      float2 st;
      st.x = mkA.x ? NEG_INF : (d0 + qc);
      st.y = mkA.y ? NEG_INF : (d1 + qc);
      *(float2*)(scores + (size_t)b * SS + s) = st;
    }
    float e0 = mkA.x ? 0.f : __expf(d0);
    float e1 = mkA.y ? 0.f : __expf(d1);
    l += e0 + e1;
    u0.x += e0*a0a.x + e1*a1a.x; u0.y += e0*a0a.y + e1*a1a.y;
    u0.z += e0*a0a.z + e1*a1a.z; u0.w += e0*a0a.w + e1*a1a.w;
    u1.x += e0*a0b.x + e1*a1b.x; u1.y += e0*a0b.y + e1*a1b.y;
    u1.z += e0*a0b.z + e1*a1b.z; u1.w += e0*a0b.w + e1*a1b.w;
    // rotate A <- B <- C
    a0a = b0a; a0b = b0b; a1a = b1a; a1b = b1b; mkA = mkB;
    b0a = c0a; b0b = c0b; b1a = c1a; b1b = c1b; mkB = mkC;
    s += 8;
  }

  // block combine across 4 waves: plain sums (no max weighting needed)
  __shared__ float ls_l[4];
  __shared__ __align__(16) float ls_u[4][DD];
  ls_u[wave][4 * lane + 0] = u0.x; ls_u[wave][4 * lane + 1] = u0.y;
  ls_u[wave][4 * lane + 2] = u0.z; ls_u[wave][4 * lane + 3] = u0.w;
  ls_u[wave][256 + 4 * lane + 0] = u1.x; ls_u[wave][256 + 4 * lane + 1] = u1.y;
  ls_u[wave][256 + 4 * lane + 2] = u1.z; ls_u[wave][256 + 4 * lane + 3] = u1.w;
  if (lane == 0) ls_l[wave] = l;
  __syncthreads();

  int d = threadIdx.x;  // 0..255
  float ua = ls_u[0][d] + ls_u[1][d] + ls_u[2][d] + ls_u[3][d];
  float ub = ls_u[0][d + 256] + ls_u[1][d + 256] + ls_u[2][d + 256] + ls_u[3][d + 256];
  float* part = partials + (size_t)(b * BPB + pb) * (DD + 2);
  part[2 + d] = ua;
  part[2 + 256 + d] = ub;
  if (threadIdx.x == 0) {
    part[0] = ls_l[0] + ls_l[1] + ls_l[2] + ls_l[3];
  }
}

// K2: fused combine + attn. 256 blocks (b, hc) x 256 threads.
__global__ __launch_bounds__(256) void k_out(
    const float* __restrict__ Wk, const float* __restrict__ bk,
    const float* __restrict__ partials, float* __restrict__ attn)
{
  int b = blockIdx.x >> 4;
  int hc = blockIdx.x & 15;
  int tid = threadIdx.x;
  int wave = tid >> 6, lane = tid & 63;
  __shared__ __align__(16) float ubar[DD];
  __shared__ float dsh;
  const float* pbase = partials + (size_t)b * BPB * (DD + 2);

  if (tid < 64) {
    float lp = pbase[tid * (DD + 2)];
    float dn = wave_red_sum(lp);
    if (tid == 63) dsh = dn;
  }
  __syncthreads();

  float inv = 1.f / dsh;
  float ua = 0.f, ub_ = 0.f;
  #pragma unroll 8
  for (int p = 0; p < BPB; ++p) {
    ua  += pbase[p * (DD + 2) + 2 + tid];
    ub_ += pbase[p * (DD + 2) + 2 + 256 + tid];
  }
  ubar[tid] = ua * inv;
  ubar[tid + 256] = ub_ * inv;
  __syncthreads();

  const float4* ub4 = (const float4*)ubar;
  float4 x0 = ub4[lane], x1 = ub4[64 + lane];
  #pragma unroll
  for (int j = 0; j < 8; ++j) {
    int h = hc * 32 + wave * 8 + j;
    const float4* wr = (const float4*)(Wk + (size_t)h * DD);
    float p = wave_red_sum(dot8(wr[lane], wr[64 + lane], x0, x1));
    if (lane == 63) attn[b * HH + h] = p + bk[h];
  }
}

extern "C" void kernel_launch(void* const* d_in, const int* in_sizes, int n_in,
                              void* d_out, int out_size, void* d_ws, size_t ws_size,
                              hipStream_t stream) {
  const float* query = (const float*)d_in[0];
  const float* key   = (const float*)d_in[1];
  const int*   mask  = (const int*)d_in[2];
  const float* Wq    = (const float*)d_in[3];
  const float* bq    = (const float*)d_in[4];
  const float* Wk    = (const float*)d_in[5];
  const float* bk    = (const float*)d_in[6];
  const float* wout  = (const float*)d_in[7];

  float* out    = (float*)d_out;
  float* attn   = out;                 // (B, H)
  float* scores = out + BB * HH;       // (B, S)
  float* ws     = (float*)d_ws;

  // ws layout (floats)
  float* ws_v  = ws;            // 512
  float* ws_w2 = ws + 512;      // 512
  float* ws_c0 = ws + 1024;     // 1 (pad to 1040)
  float* partials = ws + 1040;  // B*BPB*(D+2) ~ 2.06 MB

  k_prep<<<dim3(129), dim3(256), 0, stream>>>(Wq, Wk, wout, bq, bk,
                                              ws_v, ws_w2, ws_c0);
  k_score<<<dim3(BB * BPB), dim3(256), 0, stream>>>(key, mask, query, ws_v,
                                                    ws_w2, ws_c0, scores, partials);
  k_out<<<dim3(BB * 16), dim3(256), 0, stream>>>(Wk, bk, partials, attn);
}